// Round 2
// baseline (1156.133 us; speedup 1.0000x reference)
//
#include <hip/hip_runtime.h>
#include <hip/hip_bf16.h>

typedef short bf16x8 __attribute__((ext_vector_type(8)));
typedef float f32x4 __attribute__((ext_vector_type(4)));

#define N_USER 50000
#define N_ITEM 50000
#define IN_DIM 256
#define HID 128
#define OUT_DIM 64
#define NEDGE 200000

__device__ __forceinline__ float bf2f(unsigned short u) {
    union { unsigned int i; float f; } v; v.i = ((unsigned int)u) << 16; return v.f;
}
__device__ __forceinline__ unsigned short f2bf(float f) {
    union { float f; unsigned int i; } v; v.f = f;
    return (unsigned short)((v.i + 0x7fffu + ((v.i >> 16) & 1u)) >> 16);
}
__device__ __forceinline__ float elu_f(float x) {
    return x > 0.f ? x : (__expf(x) - 1.f);
}

// h = x @ W_proj + b_proj ; x: [M,256] f32, W: [256,128] f32, h: [M,128] bf16 (ws)
// One wave per 16-row strip; MFMA 16x16x32 bf16 with on-the-fly f32->bf16 casts.
__global__ __launch_bounds__(256) void proj_kernel(
    const float* __restrict__ x, const float* __restrict__ W,
    const float* __restrict__ b, unsigned short* __restrict__ h, int M)
{
    int wid  = threadIdx.x >> 6;
    int lane = threadIdx.x & 63;
    int strip = blockIdx.x * 4 + wid;
    int row0 = strip * 16;
    if (row0 >= M) return;

    int r  = lane & 15;   // A-row / B-col within tile
    int kg = lane >> 4;   // k-group 0..3

    // A frags: x[row0+r][kb*32 + kg*8 + j], float4-vectorized loads, cast to bf16
    bf16x8 a[8];
    const float* xrow = x + (size_t)(row0 + r) * IN_DIM;
    #pragma unroll
    for (int kb = 0; kb < 8; ++kb) {
        float4 v0 = *(const float4*)(xrow + kb * 32 + kg * 8);
        float4 v1 = *(const float4*)(xrow + kb * 32 + kg * 8 + 4);
        a[kb][0] = (short)f2bf(v0.x); a[kb][1] = (short)f2bf(v0.y);
        a[kb][2] = (short)f2bf(v0.z); a[kb][3] = (short)f2bf(v0.w);
        a[kb][4] = (short)f2bf(v1.x); a[kb][5] = (short)f2bf(v1.y);
        a[kb][6] = (short)f2bf(v1.z); a[kb][7] = (short)f2bf(v1.w);
    }

    #pragma unroll
    for (int nt = 0; nt < 8; ++nt) {
        f32x4 c = {0.f, 0.f, 0.f, 0.f};
        #pragma unroll
        for (int kb = 0; kb < 8; ++kb) {
            bf16x8 bf;
            #pragma unroll
            for (int j = 0; j < 8; ++j)
                bf[j] = (short)f2bf(W[(size_t)(kb * 32 + kg * 8 + j) * HID + nt * 16 + r]);
            c = __builtin_amdgcn_mfma_f32_16x16x32_bf16(a[kb], bf, c, 0, 0, 0);
        }
        float bias = b[nt * 16 + r];
        #pragma unroll
        for (int i = 0; i < 4; ++i) {
            int rr = row0 + kg * 4 + i;  // C/D: row=(lane>>4)*4+reg, col=lane&15
            h[(size_t)rr * HID + nt * 16 + r] = f2bf(c[i] + bias);
        }
    }
}

// scatter: acc[dst] += al*h_src[src] + ar*h_dst[dst] over edges. 32 lanes per edge.
__global__ __launch_bounds__(256) void edge_kernel(
    const unsigned short* __restrict__ h_src, const unsigned short* __restrict__ h_dst,
    const int* __restrict__ edges, int E,
    const float* __restrict__ al_p, const float* __restrict__ ar_p,
    float* __restrict__ acc)
{
    float al = al_p[0];
    float ar = ar_p[0];
    int g    = (int)((blockIdx.x * blockDim.x + threadIdx.x) >> 5);  // edge id
    int lane = threadIdx.x & 31;
    if (g >= E) return;

    int2 sd = *(const int2*)(edges + 2 * (size_t)g);
    const ushort4 hs = *(const ushort4*)(h_src + (size_t)sd.x * HID + lane * 4);
    const ushort4 hd = *(const ushort4*)(h_dst + (size_t)sd.y * HID + lane * 4);
    float* ap = acc + (size_t)sd.y * HID + lane * 4;
    atomicAdd(ap + 0, al * bf2f(hs.x) + ar * bf2f(hd.x));
    atomicAdd(ap + 1, al * bf2f(hs.y) + ar * bf2f(hd.y));
    atomicAdd(ap + 2, al * bf2f(hs.z) + ar * bf2f(hd.z));
    atomicAdd(ap + 3, al * bf2f(hs.w) + ar * bf2f(hd.w));
}

// out_u = elu(acc_u) @ W_out + b_out ; acc: [M,128] f32, W_out: [128,64] f32, out: [M,64] f32
__global__ __launch_bounds__(256) void out_user_kernel(
    const float* __restrict__ acc, const float* __restrict__ Wo,
    const float* __restrict__ bo, float* __restrict__ out, int M)
{
    int wid  = threadIdx.x >> 6;
    int lane = threadIdx.x & 63;
    int strip = blockIdx.x * 4 + wid;
    int row0 = strip * 16;
    if (row0 >= M) return;

    int r  = lane & 15;
    int kg = lane >> 4;

    bf16x8 a[4];
    const float* arow = acc + (size_t)(row0 + r) * HID;
    #pragma unroll
    for (int kb = 0; kb < 4; ++kb) {
        #pragma unroll
        for (int j = 0; j < 8; ++j) {
            float v = arow[kb * 32 + kg * 8 + j];
            v = elu_f(v);
            a[kb][j] = (short)f2bf(v);
        }
    }

    #pragma unroll
    for (int nt = 0; nt < 4; ++nt) {
        f32x4 c = {0.f, 0.f, 0.f, 0.f};
        #pragma unroll
        for (int kb = 0; kb < 4; ++kb) {
            bf16x8 bf;
            #pragma unroll
            for (int j = 0; j < 8; ++j)
                bf[j] = (short)f2bf(Wo[(size_t)(kb * 32 + kg * 8 + j) * OUT_DIM + nt * 16 + r]);
            c = __builtin_amdgcn_mfma_f32_16x16x32_bf16(a[kb], bf, c, 0, 0, 0);
        }
        float bias = bo[nt * 16 + r];
        #pragma unroll
        for (int i = 0; i < 4; ++i)
            out[(size_t)(row0 + kg * 4 + i) * OUT_DIM + nt * 16 + r] = c[i] + bias;
    }
}

// out_i = elu(acc_i), elementwise f32 -> f32
__global__ __launch_bounds__(256) void out_item_kernel(
    const float* __restrict__ acc, float* __restrict__ out, int n4)
{
    int i = blockIdx.x * 256 + threadIdx.x;
    if (i >= n4) return;
    float4 v = *(const float4*)(acc + (size_t)i * 4);
    float4 o;
    o.x = elu_f(v.x);
    o.y = elu_f(v.y);
    o.z = elu_f(v.z);
    o.w = elu_f(v.w);
    *(float4*)(out + (size_t)i * 4) = o;
}

extern "C" void kernel_launch(void* const* d_in, const int* in_sizes, int n_in,
                              void* d_out, int out_size, void* d_ws, size_t ws_size,
                              hipStream_t stream)
{
    const float* x_user = (const float*)d_in[0];
    const float* x_item = (const float*)d_in[1];
    const float* W_proj = (const float*)d_in[2];
    const float* b_proj = (const float*)d_in[3];
    const float* al_uu  = (const float*)d_in[4];
    const float* ar_uu  = (const float*)d_in[5];
    const float* al_iu  = (const float*)d_in[6];
    const float* ar_iu  = (const float*)d_in[7];
    const float* al_ui  = (const float*)d_in[8];
    const float* ar_ui  = (const float*)d_in[9];
    const float* W_out  = (const float*)d_in[10];
    const float* b_out  = (const float*)d_in[11];
    const int* edges_uu = (const int*)d_in[12];
    const int* edges_iu = (const int*)d_in[13];
    const int* edges_ui = (const int*)d_in[14];

    char* ws = (char*)d_ws;
    float* acc_u = (float*)(ws);                                  // 25,600,000 B
    float* acc_i = (float*)(ws + 25600000);                       // 25,600,000 B
    unsigned short* h_u = (unsigned short*)(ws + 51200000);       // 12,800,000 B
    unsigned short* h_i = (unsigned short*)(ws + 64000000);       // 12,800,000 B

    float* out_u = (float*)d_out;
    float* out_i = out_u + (size_t)N_USER * OUT_DIM;

    // zero the f32 accumulators (ws is poisoned once, not re-poisoned between replays)
    hipMemsetAsync(d_ws, 0, 51200000, stream);

    dim3 blk(256);
    proj_kernel<<<dim3(782), blk, 0, stream>>>(x_user, W_proj, b_proj, h_u, N_USER);
    proj_kernel<<<dim3(782), blk, 0, stream>>>(x_item, W_proj, b_proj, h_i, N_ITEM);

    edge_kernel<<<dim3(25000), blk, 0, stream>>>(h_u, h_u, edges_uu, NEDGE, al_uu, ar_uu, acc_u);
    edge_kernel<<<dim3(25000), blk, 0, stream>>>(h_i, h_u, edges_iu, NEDGE, al_iu, ar_iu, acc_u);
    edge_kernel<<<dim3(25000), blk, 0, stream>>>(h_u, h_i, edges_ui, NEDGE, al_ui, ar_ui, acc_i);

    out_user_kernel<<<dim3(782), blk, 0, stream>>>(acc_u, W_out, b_out, out_u, N_USER);
    out_item_kernel<<<dim3(6250), blk, 0, stream>>>(acc_i, out_i, 1600000);
}

// Round 3
// 212.150 us; speedup vs baseline: 5.4496x; 5.4496x over previous
//
#include <hip/hip_runtime.h>
#include <hip/hip_bf16.h>

typedef short bf16x8 __attribute__((ext_vector_type(8)));
typedef float f32x4 __attribute__((ext_vector_type(4)));

#define N_USER 50000
#define N_ITEM 50000
#define IN_DIM 256
#define HID 128
#define OUT_DIM 64
#define NEDGE 200000
#define CAP 32

__device__ __forceinline__ float bf2f(unsigned short u) {
    union { unsigned int i; float f; } v; v.i = ((unsigned int)u) << 16; return v.f;
}
__device__ __forceinline__ unsigned short f2bf(float f) {
    union { float f; unsigned int i; } v; v.f = f;
    return (unsigned short)((v.i + 0x7fffu + ((v.i >> 16) & 1u)) >> 16);
}
__device__ __forceinline__ float elu_f(float x) {
    return x > 0.f ? x : (__expf(x) - 1.f);
}

// ---- transpose weights to bf16 once per launch ----
// Wt_proj[n][k] = bf16(W_proj[k][n])  (128 x 256)
// Wt_out [n][k] = bf16(W_out [k][n])  (64 x 128)
__global__ __launch_bounds__(256) void transpose_w_kernel(
    const float* __restrict__ Wp, const float* __restrict__ Wo,
    unsigned short* __restrict__ Wtp, unsigned short* __restrict__ Wto)
{
    int tid = blockIdx.x * 256 + threadIdx.x;
    if (tid < HID * IN_DIM) {
        int n = tid >> 8, k = tid & 255;          // n<128, k<256
        Wtp[tid] = f2bf(Wp[(size_t)k * HID + n]);
    } else {
        int t = tid - HID * IN_DIM;
        if (t < OUT_DIM * HID) {
            int n = t >> 7, k = t & 127;          // n<64, k<128
            Wto[t] = f2bf(Wo[(size_t)k * OUT_DIM + n]);
        }
    }
}

// h = bf16(x @ W_proj + b_proj); x: [M,256] f32, Wt: [128,256] bf16 (transposed), h: [M,128] bf16
__global__ __launch_bounds__(256) void proj_kernel(
    const float* __restrict__ x, const unsigned short* __restrict__ Wt,
    const float* __restrict__ b, unsigned short* __restrict__ h, int M)
{
    int wid  = threadIdx.x >> 6;
    int lane = threadIdx.x & 63;
    int row0 = (blockIdx.x * 4 + wid) * 16;
    if (row0 >= M) return;

    int r  = lane & 15;   // A-row / B-col within tile
    int kg = lane >> 4;   // k-group 0..3

    bf16x8 a[8];
    const float* xrow = x + (size_t)(row0 + r) * IN_DIM;
    #pragma unroll
    for (int kb = 0; kb < 8; ++kb) {
        float4 v0 = *(const float4*)(xrow + kb * 32 + kg * 8);
        float4 v1 = *(const float4*)(xrow + kb * 32 + kg * 8 + 4);
        a[kb][0] = (short)f2bf(v0.x); a[kb][1] = (short)f2bf(v0.y);
        a[kb][2] = (short)f2bf(v0.z); a[kb][3] = (short)f2bf(v0.w);
        a[kb][4] = (short)f2bf(v1.x); a[kb][5] = (short)f2bf(v1.y);
        a[kb][6] = (short)f2bf(v1.z); a[kb][7] = (short)f2bf(v1.w);
    }

    #pragma unroll
    for (int nt = 0; nt < 8; ++nt) {
        f32x4 c = {0.f, 0.f, 0.f, 0.f};
        const unsigned short* wrow = Wt + (size_t)(nt * 16 + r) * IN_DIM;
        #pragma unroll
        for (int kb = 0; kb < 8; ++kb) {
            bf16x8 bf = *(const bf16x8*)(wrow + kb * 32 + kg * 8);
            c = __builtin_amdgcn_mfma_f32_16x16x32_bf16(a[kb], bf, c, 0, 0, 0);
        }
        float bias = b[nt * 16 + r];
        #pragma unroll
        for (int i = 0; i < 4; ++i) {
            int rr = row0 + kg * 4 + i;  // C/D: row=(lane>>4)*4+reg, col=lane&15
            h[(size_t)rr * HID + nt * 16 + r] = f2bf(c[i] + bias);
        }
    }
}

// bucket fill: one thread per edge; slot = atomicAdd(cnt[dst]); bucket[dst*CAP+slot]=src
__global__ __launch_bounds__(256) void fill_kernel(
    const int* __restrict__ e_uu, const int* __restrict__ e_iu, const int* __restrict__ e_ui,
    int* __restrict__ cnt, int* __restrict__ bkt)  // cnt: [3][50000], bkt: [3][50000*CAP]
{
    int rel = blockIdx.y;
    const int* e = rel == 0 ? e_uu : (rel == 1 ? e_iu : e_ui);
    int g = blockIdx.x * 256 + threadIdx.x;
    if (g >= NEDGE) return;
    int2 sd = *(const int2*)(e + 2 * (size_t)g);
    int* c = cnt + (size_t)rel * N_USER;
    int* bk = bkt + (size_t)rel * N_USER * CAP;
    int slot = atomicAdd(&c[sd.y], 1);
    if (slot < CAP) bk[(size_t)sd.y * CAP + slot] = sd.x;
}

// user gather: one wave per dst user v (lane handles 2 cols as bf16 pair)
// g_u[v] = bf16(elu( al_uu*S_uu + al_iu*S_iu + (ar_uu*deg_uu + ar_iu*deg_iu)*h_u[v] ))
__global__ __launch_bounds__(256) void gather_user_kernel(
    const unsigned short* __restrict__ h_u, const unsigned short* __restrict__ h_i,
    const int* __restrict__ cnt, const int* __restrict__ bkt,
    const float* __restrict__ al_uu, const float* __restrict__ ar_uu,
    const float* __restrict__ al_iu, const float* __restrict__ ar_iu,
    unsigned short* __restrict__ g_u)
{
    int v = blockIdx.x * 4 + (threadIdx.x >> 6);
    if (v >= N_USER) return;
    int lane = threadIdx.x & 63;

    unsigned int hv = *(const unsigned int*)(h_u + (size_t)v * HID + lane * 2);
    float hv0 = bf2f((unsigned short)hv), hv1 = bf2f((unsigned short)(hv >> 16));

    int d_uu = cnt[v];
    int d_iu = cnt[N_USER + v];
    float rscale = ar_uu[0] * (float)d_uu + ar_iu[0] * (float)d_iu;
    float acc0 = rscale * hv0, acc1 = rscale * hv1;

    const int* b_uu = bkt + (size_t)v * CAP;
    int n = min(d_uu, CAP);
    float s0 = 0.f, s1 = 0.f;
    for (int j = 0; j < n; ++j) {
        int src = b_uu[j];
        unsigned int u = *(const unsigned int*)(h_u + (size_t)src * HID + lane * 2);
        s0 += bf2f((unsigned short)u);
        s1 += bf2f((unsigned short)(u >> 16));
    }
    acc0 += al_uu[0] * s0; acc1 += al_uu[0] * s1;

    const int* b_iu = bkt + (size_t)N_USER * CAP + (size_t)v * CAP;
    n = min(d_iu, CAP);
    s0 = 0.f; s1 = 0.f;
    for (int j = 0; j < n; ++j) {
        int src = b_iu[j];
        unsigned int u = *(const unsigned int*)(h_i + (size_t)src * HID + lane * 2);
        s0 += bf2f((unsigned short)u);
        s1 += bf2f((unsigned short)(u >> 16));
    }
    acc0 += al_iu[0] * s0; acc1 += al_iu[0] * s1;

    unsigned int o = (unsigned int)f2bf(elu_f(acc0)) | ((unsigned int)f2bf(elu_f(acc1)) << 16);
    *(unsigned int*)(g_u + (size_t)v * HID + lane * 2) = o;
}

// item gather: one wave per dst item v; writes final f32 out_i row (ELU applied)
__global__ __launch_bounds__(256) void gather_item_kernel(
    const unsigned short* __restrict__ h_u, const unsigned short* __restrict__ h_i,
    const int* __restrict__ cnt, const int* __restrict__ bkt,
    const float* __restrict__ al_ui, const float* __restrict__ ar_ui,
    float* __restrict__ out_i)
{
    int v = blockIdx.x * 4 + (threadIdx.x >> 6);
    if (v >= N_ITEM) return;
    int lane = threadIdx.x & 63;

    unsigned int hv = *(const unsigned int*)(h_i + (size_t)v * HID + lane * 2);
    float hv0 = bf2f((unsigned short)hv), hv1 = bf2f((unsigned short)(hv >> 16));

    int d = cnt[2 * N_USER + v];
    float rscale = ar_ui[0] * (float)d;
    float s0 = 0.f, s1 = 0.f;
    const int* bk = bkt + 2 * (size_t)N_USER * CAP + (size_t)v * CAP;
    int n = min(d, CAP);
    for (int j = 0; j < n; ++j) {
        int src = bk[j];
        unsigned int u = *(const unsigned int*)(h_u + (size_t)src * HID + lane * 2);
        s0 += bf2f((unsigned short)u);
        s1 += bf2f((unsigned short)(u >> 16));
    }
    float2 o;
    o.x = elu_f(rscale * hv0 + al_ui[0] * s0);
    o.y = elu_f(rscale * hv1 + al_ui[0] * s1);
    *(float2*)(out_i + (size_t)v * HID + lane * 2) = o;
}

// out_u = g_u @ W_out + b_out ; g_u: [M,128] bf16, Wto: [64,128] bf16 (transposed), out: [M,64] f32
__global__ __launch_bounds__(256) void out_user_kernel(
    const unsigned short* __restrict__ g_u, const unsigned short* __restrict__ Wto,
    const float* __restrict__ bo, float* __restrict__ out, int M)
{
    int wid  = threadIdx.x >> 6;
    int lane = threadIdx.x & 63;
    int row0 = (blockIdx.x * 4 + wid) * 16;
    if (row0 >= M) return;

    int r  = lane & 15;
    int kg = lane >> 4;

    bf16x8 a[4];
    const unsigned short* grow = g_u + (size_t)(row0 + r) * HID;
    #pragma unroll
    for (int kb = 0; kb < 4; ++kb)
        a[kb] = *(const bf16x8*)(grow + kb * 32 + kg * 8);

    #pragma unroll
    for (int nt = 0; nt < 4; ++nt) {
        f32x4 c = {0.f, 0.f, 0.f, 0.f};
        const unsigned short* wrow = Wto + (size_t)(nt * 16 + r) * HID;
        #pragma unroll
        for (int kb = 0; kb < 4; ++kb) {
            bf16x8 bf = *(const bf16x8*)(wrow + kb * 32 + kg * 8);
            c = __builtin_amdgcn_mfma_f32_16x16x32_bf16(a[kb], bf, c, 0, 0, 0);
        }
        float bias = bo[nt * 16 + r];
        #pragma unroll
        for (int i = 0; i < 4; ++i)
            out[(size_t)(row0 + kg * 4 + i) * OUT_DIM + nt * 16 + r] = c[i] + bias;
    }
}

extern "C" void kernel_launch(void* const* d_in, const int* in_sizes, int n_in,
                              void* d_out, int out_size, void* d_ws, size_t ws_size,
                              hipStream_t stream)
{
    const float* x_user = (const float*)d_in[0];
    const float* x_item = (const float*)d_in[1];
    const float* W_proj = (const float*)d_in[2];
    const float* b_proj = (const float*)d_in[3];
    const float* al_uu  = (const float*)d_in[4];
    const float* ar_uu  = (const float*)d_in[5];
    const float* al_iu  = (const float*)d_in[6];
    const float* ar_iu  = (const float*)d_in[7];
    const float* al_ui  = (const float*)d_in[8];
    const float* ar_ui  = (const float*)d_in[9];
    const float* W_out  = (const float*)d_in[10];
    const float* b_out  = (const float*)d_in[11];
    const int* edges_uu = (const int*)d_in[12];
    const int* edges_iu = (const int*)d_in[13];
    const int* edges_ui = (const int*)d_in[14];

    char* ws = (char*)d_ws;
    unsigned short* h_u = (unsigned short*)(ws);                   // 12,800,000
    unsigned short* h_i = (unsigned short*)(ws + 12800000);        // 12,800,000
    unsigned short* g_u = (unsigned short*)(ws + 25600000);        // 12,800,000
    unsigned short* Wtp = (unsigned short*)(ws + 38400000);        //     65,536
    unsigned short* Wto = (unsigned short*)(ws + 38465536);        //     16,384
    int* cnt            = (int*)(ws + 38481920);                   //    600,000 (3 x 50000)
    int* bkt            = (int*)(ws + 39081920);                   // 19,200,000 (3 x 50000 x 32)

    float* out_u = (float*)d_out;
    float* out_i = out_u + (size_t)N_USER * OUT_DIM;

    // zero only the degree counters each launch
    hipMemsetAsync(cnt, 0, 3 * N_USER * sizeof(int), stream);

    dim3 blk(256);
    transpose_w_kernel<<<dim3(160), blk, 0, stream>>>(W_proj, W_out, Wtp, Wto);
    proj_kernel<<<dim3(782), blk, 0, stream>>>(x_user, Wtp, b_proj, h_u, N_USER);
    proj_kernel<<<dim3(782), blk, 0, stream>>>(x_item, Wtp, b_proj, h_i, N_ITEM);

    fill_kernel<<<dim3(782, 3), blk, 0, stream>>>(edges_uu, edges_iu, edges_ui, cnt, bkt);

    gather_user_kernel<<<dim3(12500), blk, 0, stream>>>(h_u, h_i, cnt, bkt,
                                                        al_uu, ar_uu, al_iu, ar_iu, g_u);
    gather_item_kernel<<<dim3(12500), blk, 0, stream>>>(h_u, h_i, cnt, bkt,
                                                        al_ui, ar_ui, out_i);

    out_user_kernel<<<dim3(782), blk, 0, stream>>>(g_u, Wto, b_out, out_u, N_USER);
}

// Round 4
// 175.738 us; speedup vs baseline: 6.5787x; 1.2072x over previous
//
#include <hip/hip_runtime.h>
#include <hip/hip_bf16.h>

typedef short bf16x8 __attribute__((ext_vector_type(8)));
typedef float f32x4 __attribute__((ext_vector_type(4)));

#define N_USER 50000
#define N_ITEM 50000
#define IN_DIM 256
#define HID 128
#define OUT_DIM 64
#define NEDGE 200000
#define CAP 32

__device__ __forceinline__ float bf2f(unsigned short u) {
    union { unsigned int i; float f; } v; v.i = ((unsigned int)u) << 16; return v.f;
}
__device__ __forceinline__ unsigned short f2bf(float f) {
    union { float f; unsigned int i; } v; v.f = f;
    return (unsigned short)((v.i + 0x7fffu + ((v.i >> 16) & 1u)) >> 16);
}
// packed f32x2 -> bf16x2 (dst.lo = cvt(a), dst.hi = cvt(b))
__device__ __forceinline__ unsigned int cvt_pk_bf16(float a, float b) {
    unsigned int r;
    asm("v_cvt_pk_bf16_f32 %0, %1, %2" : "=v"(r) : "v"(a), "v"(b));
    return r;
}
__device__ __forceinline__ float elu_f(float x) {
    return x > 0.f ? x : (__expf(x) - 1.f);
}

// ---- transpose weights to bf16 once per launch ----
__global__ __launch_bounds__(256) void transpose_w_kernel(
    const float* __restrict__ Wp, const float* __restrict__ Wo,
    unsigned short* __restrict__ Wtp, unsigned short* __restrict__ Wto)
{
    int tid = blockIdx.x * 256 + threadIdx.x;
    if (tid < HID * IN_DIM) {
        int n = tid >> 8, k = tid & 255;          // n<128, k<256
        Wtp[tid] = f2bf(Wp[(size_t)k * HID + n]);
    } else {
        int t = tid - HID * IN_DIM;
        if (t < OUT_DIM * HID) {
            int n = t >> 7, k = t & 127;          // n<64, k<128
            Wto[t] = f2bf(Wo[(size_t)k * OUT_DIM + n]);
        }
    }
}

// h = bf16(x @ W_proj + b_proj); x: [M,256] f32, Wt: [128,256] bf16 (transposed), h: [M,128] bf16
__global__ __launch_bounds__(256) void proj_kernel(
    const float* __restrict__ x, const unsigned short* __restrict__ Wt,
    const float* __restrict__ b, unsigned short* __restrict__ h, int M)
{
    int wid  = threadIdx.x >> 6;
    int lane = threadIdx.x & 63;
    int row0 = (blockIdx.x * 4 + wid) * 16;
    if (row0 >= M) return;

    int r  = lane & 15;   // A-row / B-col within tile
    int kg = lane >> 4;   // k-group 0..3

    bf16x8 a[8];
    const float* xrow = x + (size_t)(row0 + r) * IN_DIM;
    #pragma unroll
    for (int kb = 0; kb < 8; ++kb) {
        float4 v0 = *(const float4*)(xrow + kb * 32 + kg * 8);
        float4 v1 = *(const float4*)(xrow + kb * 32 + kg * 8 + 4);
        unsigned int* au = (unsigned int*)&a[kb];
        au[0] = cvt_pk_bf16(v0.x, v0.y);
        au[1] = cvt_pk_bf16(v0.z, v0.w);
        au[2] = cvt_pk_bf16(v1.x, v1.y);
        au[3] = cvt_pk_bf16(v1.z, v1.w);
    }

    #pragma unroll
    for (int nt = 0; nt < 8; ++nt) {
        f32x4 c = {0.f, 0.f, 0.f, 0.f};
        const unsigned short* wrow = Wt + (size_t)(nt * 16 + r) * IN_DIM;
        #pragma unroll
        for (int kb = 0; kb < 8; ++kb) {
            bf16x8 bf = *(const bf16x8*)(wrow + kb * 32 + kg * 8);
            c = __builtin_amdgcn_mfma_f32_16x16x32_bf16(a[kb], bf, c, 0, 0, 0);
        }
        float bias = b[nt * 16 + r];
        #pragma unroll
        for (int i = 0; i < 4; ++i) {
            int rr = row0 + kg * 4 + i;  // C/D: row=(lane>>4)*4+reg, col=lane&15
            h[(size_t)rr * HID + nt * 16 + r] = f2bf(c[i] + bias);
        }
    }
}

// bucket fill: one thread per edge; slot = atomicAdd(cnt[dst]); bucket[dst*CAP+slot]=src
__global__ __launch_bounds__(256) void fill_kernel(
    const int* __restrict__ e_uu, const int* __restrict__ e_iu, const int* __restrict__ e_ui,
    int* __restrict__ cnt, int* __restrict__ bkt)
{
    int rel = blockIdx.y;
    const int* e = rel == 0 ? e_uu : (rel == 1 ? e_iu : e_ui);
    int g = blockIdx.x * 256 + threadIdx.x;
    if (g >= NEDGE) return;
    int2 sd = *(const int2*)(e + 2 * (size_t)g);
    int* c = cnt + (size_t)rel * N_USER;
    int* bk = bkt + (size_t)rel * N_USER * CAP;
    int slot = atomicAdd(&c[sd.y], 1);
    if (slot < CAP) bk[(size_t)sd.y * CAP + slot] = sd.x;
}

// user gather: one wave per dst user v; 8 predicated independent row loads per relation
__global__ __launch_bounds__(256) void gather_user_kernel(
    const unsigned short* __restrict__ h_u, const unsigned short* __restrict__ h_i,
    const int* __restrict__ cnt, const int* __restrict__ bkt,
    const float* __restrict__ al_uu, const float* __restrict__ ar_uu,
    const float* __restrict__ al_iu, const float* __restrict__ ar_iu,
    unsigned short* __restrict__ g_u)
{
    int v = blockIdx.x * 4 + (threadIdx.x >> 6);
    if (v >= N_USER) return;
    int lane = threadIdx.x & 63;

    unsigned int hv = *(const unsigned int*)(h_u + (size_t)v * HID + lane * 2);

    int d_uu = cnt[v];
    int d_iu = cnt[N_USER + v];

    // 8 bucket indices per relation via wave-uniform int4 loads
    const int4* b0 = (const int4*)(bkt + (size_t)v * CAP);
    const int4* b1 = (const int4*)(bkt + (size_t)N_USER * CAP + (size_t)v * CAP);
    int4 q0a = b0[0], q0b = b0[1];
    int4 q1a = b1[0], q1b = b1[1];
    int idx0[8] = {q0a.x, q0a.y, q0a.z, q0a.w, q0b.x, q0b.y, q0b.z, q0b.w};
    int idx1[8] = {q1a.x, q1a.y, q1a.z, q1a.w, q1b.x, q1b.y, q1b.z, q1b.w};

    float s0u = 0.f, s1u = 0.f, s0i = 0.f, s1i = 0.f;
    unsigned int ru[8], ri[8];
    #pragma unroll
    for (int j = 0; j < 8; ++j) {
        int s = j < d_uu ? idx0[j] : v;
        ru[j] = *(const unsigned int*)(h_u + (size_t)s * HID + lane * 2);
    }
    #pragma unroll
    for (int j = 0; j < 8; ++j) {
        int s = j < d_iu ? idx1[j] : v;
        ri[j] = *(const unsigned int*)(h_i + (size_t)s * HID + lane * 2);
    }
    #pragma unroll
    for (int j = 0; j < 8; ++j) {
        float mu = j < d_uu ? 1.f : 0.f;
        float mi = j < d_iu ? 1.f : 0.f;
        s0u += mu * bf2f((unsigned short)ru[j]);
        s1u += mu * bf2f((unsigned short)(ru[j] >> 16));
        s0i += mi * bf2f((unsigned short)ri[j]);
        s1i += mi * bf2f((unsigned short)(ri[j] >> 16));
    }
    // rare tails (deg > 8)
    if (d_uu > 8) {
        int n = min(d_uu, CAP);
        const int* bq = bkt + (size_t)v * CAP;
        for (int j = 8; j < n; ++j) {
            unsigned int u = *(const unsigned int*)(h_u + (size_t)bq[j] * HID + lane * 2);
            s0u += bf2f((unsigned short)u);
            s1u += bf2f((unsigned short)(u >> 16));
        }
    }
    if (d_iu > 8) {
        int n = min(d_iu, CAP);
        const int* bq = bkt + (size_t)N_USER * CAP + (size_t)v * CAP;
        for (int j = 8; j < n; ++j) {
            unsigned int u = *(const unsigned int*)(h_i + (size_t)bq[j] * HID + lane * 2);
            s0i += bf2f((unsigned short)u);
            s1i += bf2f((unsigned short)(u >> 16));
        }
    }

    float rscale = ar_uu[0] * (float)d_uu + ar_iu[0] * (float)d_iu;
    float acc0 = al_uu[0] * s0u + al_iu[0] * s0i + rscale * bf2f((unsigned short)hv);
    float acc1 = al_uu[0] * s1u + al_iu[0] * s1i + rscale * bf2f((unsigned short)(hv >> 16));

    *(unsigned int*)(g_u + (size_t)v * HID + lane * 2) = cvt_pk_bf16(elu_f(acc0), elu_f(acc1));
}

// item gather: one wave per dst item v; writes final f32 out_i row (ELU applied)
__global__ __launch_bounds__(256) void gather_item_kernel(
    const unsigned short* __restrict__ h_u, const unsigned short* __restrict__ h_i,
    const int* __restrict__ cnt, const int* __restrict__ bkt,
    const float* __restrict__ al_ui, const float* __restrict__ ar_ui,
    float* __restrict__ out_i)
{
    int v = blockIdx.x * 4 + (threadIdx.x >> 6);
    if (v >= N_ITEM) return;
    int lane = threadIdx.x & 63;

    unsigned int hv = *(const unsigned int*)(h_i + (size_t)v * HID + lane * 2);

    int d = cnt[2 * N_USER + v];
    const int4* bq4 = (const int4*)(bkt + 2 * (size_t)N_USER * CAP + (size_t)v * CAP);
    int4 qa = bq4[0], qb = bq4[1];
    int idx[8] = {qa.x, qa.y, qa.z, qa.w, qb.x, qb.y, qb.z, qb.w};

    unsigned int rr[8];
    #pragma unroll
    for (int j = 0; j < 8; ++j) {
        int s = j < d ? idx[j] : v;
        rr[j] = *(const unsigned int*)(h_u + (size_t)s * HID + lane * 2);
    }
    float s0 = 0.f, s1 = 0.f;
    #pragma unroll
    for (int j = 0; j < 8; ++j) {
        float m = j < d ? 1.f : 0.f;
        s0 += m * bf2f((unsigned short)rr[j]);
        s1 += m * bf2f((unsigned short)(rr[j] >> 16));
    }
    if (d > 8) {
        int n = min(d, CAP);
        const int* bq = bkt + 2 * (size_t)N_USER * CAP + (size_t)v * CAP;
        for (int j = 8; j < n; ++j) {
            unsigned int u = *(const unsigned int*)(h_u + (size_t)bq[j] * HID + lane * 2);
            s0 += bf2f((unsigned short)u);
            s1 += bf2f((unsigned short)(u >> 16));
        }
    }

    float rscale = ar_ui[0] * (float)d;
    float2 o;
    o.x = elu_f(rscale * bf2f((unsigned short)hv) + al_ui[0] * s0);
    o.y = elu_f(rscale * bf2f((unsigned short)(hv >> 16)) + al_ui[0] * s1);
    *(float2*)(out_i + (size_t)v * HID + lane * 2) = o;
}

// out_u = g_u @ W_out + b_out ; g_u: [M,128] bf16, Wto: [64,128] bf16 (transposed), out: [M,64] f32
__global__ __launch_bounds__(256) void out_user_kernel(
    const unsigned short* __restrict__ g_u, const unsigned short* __restrict__ Wto,
    const float* __restrict__ bo, float* __restrict__ out, int M)
{
    int wid  = threadIdx.x >> 6;
    int lane = threadIdx.x & 63;
    int row0 = (blockIdx.x * 4 + wid) * 16;
    if (row0 >= M) return;

    int r  = lane & 15;
    int kg = lane >> 4;

    bf16x8 a[4];
    const unsigned short* grow = g_u + (size_t)(row0 + r) * HID;
    #pragma unroll
    for (int kb = 0; kb < 4; ++kb)
        a[kb] = *(const bf16x8*)(grow + kb * 32 + kg * 8);

    #pragma unroll
    for (int nt = 0; nt < 4; ++nt) {
        f32x4 c = {0.f, 0.f, 0.f, 0.f};
        const unsigned short* wrow = Wto + (size_t)(nt * 16 + r) * HID;
        #pragma unroll
        for (int kb = 0; kb < 4; ++kb) {
            bf16x8 bf = *(const bf16x8*)(wrow + kb * 32 + kg * 8);
            c = __builtin_amdgcn_mfma_f32_16x16x32_bf16(a[kb], bf, c, 0, 0, 0);
        }
        float bias = bo[nt * 16 + r];
        #pragma unroll
        for (int i = 0; i < 4; ++i)
            out[(size_t)(row0 + kg * 4 + i) * OUT_DIM + nt * 16 + r] = c[i] + bias;
    }
}

extern "C" void kernel_launch(void* const* d_in, const int* in_sizes, int n_in,
                              void* d_out, int out_size, void* d_ws, size_t ws_size,
                              hipStream_t stream)
{
    const float* x_user = (const float*)d_in[0];
    const float* x_item = (const float*)d_in[1];
    const float* W_proj = (const float*)d_in[2];
    const float* b_proj = (const float*)d_in[3];
    const float* al_uu  = (const float*)d_in[4];
    const float* ar_uu  = (const float*)d_in[5];
    const float* al_iu  = (const float*)d_in[6];
    const float* ar_iu  = (const float*)d_in[7];
    const float* al_ui  = (const float*)d_in[8];
    const float* ar_ui  = (const float*)d_in[9];
    const float* W_out  = (const float*)d_in[10];
    const float* b_out  = (const float*)d_in[11];
    const int* edges_uu = (const int*)d_in[12];
    const int* edges_iu = (const int*)d_in[13];
    const int* edges_ui = (const int*)d_in[14];

    char* ws = (char*)d_ws;
    unsigned short* h_u = (unsigned short*)(ws);                   // 12,800,000
    unsigned short* h_i = (unsigned short*)(ws + 12800000);        // 12,800,000
    unsigned short* g_u = (unsigned short*)(ws + 25600000);        // 12,800,000
    unsigned short* Wtp = (unsigned short*)(ws + 38400000);        //     65,536
    unsigned short* Wto = (unsigned short*)(ws + 38465536);        //     16,384
    int* cnt            = (int*)(ws + 38481920);                   //    600,000 (3 x 50000)
    int* bkt            = (int*)(ws + 39081920);                   // 19,200,000 (3 x 50000 x 32)

    float* out_u = (float*)d_out;
    float* out_i = out_u + (size_t)N_USER * OUT_DIM;

    hipMemsetAsync(cnt, 0, 3 * N_USER * sizeof(int), stream);

    dim3 blk(256);
    transpose_w_kernel<<<dim3(160), blk, 0, stream>>>(W_proj, W_out, Wtp, Wto);
    proj_kernel<<<dim3(782), blk, 0, stream>>>(x_user, Wtp, b_proj, h_u, N_USER);
    proj_kernel<<<dim3(782), blk, 0, stream>>>(x_item, Wtp, b_proj, h_i, N_ITEM);

    fill_kernel<<<dim3(782, 3), blk, 0, stream>>>(edges_uu, edges_iu, edges_ui, cnt, bkt);

    gather_user_kernel<<<dim3(12500), blk, 0, stream>>>(h_u, h_i, cnt, bkt,
                                                        al_uu, ar_uu, al_iu, ar_iu, g_u);
    gather_item_kernel<<<dim3(12500), blk, 0, stream>>>(h_u, h_i, cnt, bkt,
                                                        al_ui, ar_ui, out_i);

    out_user_kernel<<<dim3(782), blk, 0, stream>>>(g_u, Wto, b_out, out_u, N_USER);
}

// Round 5
// 127.918 us; speedup vs baseline: 9.0381x; 1.3738x over previous
//
#include <hip/hip_runtime.h>
#include <hip/hip_bf16.h>

typedef short bf16x8 __attribute__((ext_vector_type(8)));
typedef float f32x4 __attribute__((ext_vector_type(4)));

#define N_USER 50000
#define N_ITEM 50000
#define IN_DIM 256
#define HID 128
#define OUT_DIM 64
#define NEDGE 200000
#define CAP 32
#define NSTRIP 3125   // 50000/16
#define PBLK 391      // ceil(3125/8)

__device__ __forceinline__ float bf2f(unsigned short u) {
    union { unsigned int i; float f; } v; v.i = ((unsigned int)u) << 16; return v.f;
}
__device__ __forceinline__ unsigned short f2bf(float f) {
    union { float f; unsigned int i; } v; v.f = f;
    return (unsigned short)((v.i + 0x7fffu + ((v.i >> 16) & 1u)) >> 16);
}
__device__ __forceinline__ unsigned int cvt_pk_bf16(float a, float b) {
    unsigned int r;
    asm("v_cvt_pk_bf16_f32 %0, %1, %2" : "=v"(r) : "v"(a), "v"(b));
    return r;
}
__device__ __forceinline__ float elu_f(float x) {
    return x > 0.f ? x : (__expf(x) - 1.f);
}

// ---- transpose weights to bf16 once per launch ----
__global__ __launch_bounds__(256) void transpose_w_kernel(
    const float* __restrict__ Wp, const float* __restrict__ Wo,
    unsigned short* __restrict__ Wtp, unsigned short* __restrict__ Wto)
{
    int tid = blockIdx.x * 256 + threadIdx.x;
    if (tid < HID * IN_DIM) {
        int n = tid >> 8, k = tid & 255;          // n<128, k<256
        Wtp[tid] = f2bf(Wp[(size_t)k * HID + n]);
    } else {
        int t = tid - HID * IN_DIM;
        if (t < OUT_DIM * HID) {
            int n = t >> 7, k = t & 127;          // n<64, k<128
            Wto[t] = f2bf(Wo[(size_t)k * OUT_DIM + n]);
        }
    }
}

// Fused projection for users+items. Wt [128][256] bf16 staged in LDS (XOR-swizzled).
// Block = 512 threads (8 waves), each wave one 16-row strip; blocks [0,391) users, [391,782) items.
__global__ __launch_bounds__(512, 4) void proj_kernel(
    const float* __restrict__ x_u, const float* __restrict__ x_i,
    const unsigned short* __restrict__ Wt, const float* __restrict__ b,
    unsigned short* __restrict__ h_u, unsigned short* __restrict__ h_i)
{
    __shared__ unsigned short lds[HID * IN_DIM];  // 65536 B

    int tid = threadIdx.x;
    // stage Wt -> LDS with swizzle byte^=((row&7)<<4) (row stride = 512 B -> bit 9)
    #pragma unroll
    for (int it = 0; it < 8; ++it) {
        int o  = it * 8192 + tid * 16;
        int so = o ^ (((o >> 9) & 7) << 4);
        int4 w = *(const int4*)((const char*)Wt + o);
        *(int4*)((char*)lds + so) = w;
    }
    __syncthreads();

    int bid = blockIdx.x;
    const float* x = x_u;
    unsigned short* h = h_u;
    if (bid >= PBLK) { bid -= PBLK; x = x_i; h = h_i; }

    int wid  = tid >> 6;
    int lane = tid & 63;
    int strip = bid * 8 + wid;
    strip = min(strip, NSTRIP - 1);   // duplicate last strip (identical writes, benign)
    int row0 = strip * 16;
    int r  = lane & 15;
    int kg = lane >> 4;

    // A frags: x[row0+r][kb*32+kg*8 ..], f32->bf16 via packed cvt
    bf16x8 a[8];
    const float* xrow = x + (size_t)(row0 + r) * IN_DIM;
    #pragma unroll
    for (int kb = 0; kb < 8; ++kb) {
        float4 v0 = *(const float4*)(xrow + kb * 32 + kg * 8);
        float4 v1 = *(const float4*)(xrow + kb * 32 + kg * 8 + 4);
        unsigned int* au = (unsigned int*)&a[kb];
        au[0] = cvt_pk_bf16(v0.x, v0.y);
        au[1] = cvt_pk_bf16(v0.z, v0.w);
        au[2] = cvt_pk_bf16(v1.x, v1.y);
        au[3] = cvt_pk_bf16(v1.z, v1.w);
    }

    #pragma unroll
    for (int nt = 0; nt < 8; ++nt) {
        f32x4 c = {0.f, 0.f, 0.f, 0.f};
        int rowb = (nt * 16 + r) * 512;
        #pragma unroll
        for (int kb = 0; kb < 8; ++kb) {
            int addr = (rowb + kb * 64 + kg * 16) ^ ((r & 7) << 4);
            bf16x8 bf = *(const bf16x8*)((const char*)lds + addr);
            c = __builtin_amdgcn_mfma_f32_16x16x32_bf16(a[kb], bf, c, 0, 0, 0);
        }
        float bias = b[nt * 16 + r];
        #pragma unroll
        for (int i = 0; i < 4; ++i) {
            int rr = row0 + kg * 4 + i;  // C/D: row=(lane>>4)*4+reg, col=lane&15
            h[(size_t)rr * HID + nt * 16 + r] = f2bf(c[i] + bias);
        }
    }
}

// bucket fill: one thread per edge; slot = atomicAdd(cnt[dst]); bucket[dst*CAP+slot]=src
__global__ __launch_bounds__(256) void fill_kernel(
    const int* __restrict__ e_uu, const int* __restrict__ e_iu, const int* __restrict__ e_ui,
    int* __restrict__ cnt, int* __restrict__ bkt)
{
    int rel = blockIdx.y;
    const int* e = rel == 0 ? e_uu : (rel == 1 ? e_iu : e_ui);
    int g = blockIdx.x * 256 + threadIdx.x;
    if (g >= NEDGE) return;
    int2 sd = *(const int2*)(e + 2 * (size_t)g);
    int* c = cnt + (size_t)rel * N_USER;
    int* bk = bkt + (size_t)rel * N_USER * CAP;
    int slot = atomicAdd(&c[sd.y], 1);
    if (slot < CAP) bk[(size_t)sd.y * CAP + slot] = sd.x;
}

// user gather: one wave per dst user v; 8 predicated independent row loads per relation
__global__ __launch_bounds__(256) void gather_user_kernel(
    const unsigned short* __restrict__ h_u, const unsigned short* __restrict__ h_i,
    const int* __restrict__ cnt, const int* __restrict__ bkt,
    const float* __restrict__ al_uu, const float* __restrict__ ar_uu,
    const float* __restrict__ al_iu, const float* __restrict__ ar_iu,
    unsigned short* __restrict__ g_u)
{
    int v = blockIdx.x * 4 + (threadIdx.x >> 6);
    if (v >= N_USER) return;
    int lane = threadIdx.x & 63;

    unsigned int hv = *(const unsigned int*)(h_u + (size_t)v * HID + lane * 2);

    int d_uu = cnt[v];
    int d_iu = cnt[N_USER + v];

    const int4* b0 = (const int4*)(bkt + (size_t)v * CAP);
    const int4* b1 = (const int4*)(bkt + (size_t)N_USER * CAP + (size_t)v * CAP);
    int4 q0a = b0[0], q0b = b0[1];
    int4 q1a = b1[0], q1b = b1[1];
    int idx0[8] = {q0a.x, q0a.y, q0a.z, q0a.w, q0b.x, q0b.y, q0b.z, q0b.w};
    int idx1[8] = {q1a.x, q1a.y, q1a.z, q1a.w, q1b.x, q1b.y, q1b.z, q1b.w};

    float s0u = 0.f, s1u = 0.f, s0i = 0.f, s1i = 0.f;
    unsigned int ru[8], ri[8];
    #pragma unroll
    for (int j = 0; j < 8; ++j) {
        int s = j < d_uu ? idx0[j] : v;
        ru[j] = *(const unsigned int*)(h_u + (size_t)s * HID + lane * 2);
    }
    #pragma unroll
    for (int j = 0; j < 8; ++j) {
        int s = j < d_iu ? idx1[j] : v;
        ri[j] = *(const unsigned int*)(h_i + (size_t)s * HID + lane * 2);
    }
    #pragma unroll
    for (int j = 0; j < 8; ++j) {
        float mu = j < d_uu ? 1.f : 0.f;
        float mi = j < d_iu ? 1.f : 0.f;
        s0u += mu * bf2f((unsigned short)ru[j]);
        s1u += mu * bf2f((unsigned short)(ru[j] >> 16));
        s0i += mi * bf2f((unsigned short)ri[j]);
        s1i += mi * bf2f((unsigned short)(ri[j] >> 16));
    }
    if (d_uu > 8) {
        int n = min(d_uu, CAP);
        const int* bq = bkt + (size_t)v * CAP;
        for (int j = 8; j < n; ++j) {
            unsigned int u = *(const unsigned int*)(h_u + (size_t)bq[j] * HID + lane * 2);
            s0u += bf2f((unsigned short)u);
            s1u += bf2f((unsigned short)(u >> 16));
        }
    }
    if (d_iu > 8) {
        int n = min(d_iu, CAP);
        const int* bq = bkt + (size_t)N_USER * CAP + (size_t)v * CAP;
        for (int j = 8; j < n; ++j) {
            unsigned int u = *(const unsigned int*)(h_i + (size_t)bq[j] * HID + lane * 2);
            s0i += bf2f((unsigned short)u);
            s1i += bf2f((unsigned short)(u >> 16));
        }
    }

    float rscale = ar_uu[0] * (float)d_uu + ar_iu[0] * (float)d_iu;
    float acc0 = al_uu[0] * s0u + al_iu[0] * s0i + rscale * bf2f((unsigned short)hv);
    float acc1 = al_uu[0] * s1u + al_iu[0] * s1i + rscale * bf2f((unsigned short)(hv >> 16));

    *(unsigned int*)(g_u + (size_t)v * HID + lane * 2) = cvt_pk_bf16(elu_f(acc0), elu_f(acc1));
}

// item gather: one wave per dst item v; writes final f32 out_i row (ELU applied)
__global__ __launch_bounds__(256) void gather_item_kernel(
    const unsigned short* __restrict__ h_u, const unsigned short* __restrict__ h_i,
    const int* __restrict__ cnt, const int* __restrict__ bkt,
    const float* __restrict__ al_ui, const float* __restrict__ ar_ui,
    float* __restrict__ out_i)
{
    int v = blockIdx.x * 4 + (threadIdx.x >> 6);
    if (v >= N_ITEM) return;
    int lane = threadIdx.x & 63;

    unsigned int hv = *(const unsigned int*)(h_i + (size_t)v * HID + lane * 2);

    int d = cnt[2 * N_USER + v];
    const int4* bq4 = (const int4*)(bkt + 2 * (size_t)N_USER * CAP + (size_t)v * CAP);
    int4 qa = bq4[0], qb = bq4[1];
    int idx[8] = {qa.x, qa.y, qa.z, qa.w, qb.x, qb.y, qb.z, qb.w};

    unsigned int rr[8];
    #pragma unroll
    for (int j = 0; j < 8; ++j) {
        int s = j < d ? idx[j] : v;
        rr[j] = *(const unsigned int*)(h_u + (size_t)s * HID + lane * 2);
    }
    float s0 = 0.f, s1 = 0.f;
    #pragma unroll
    for (int j = 0; j < 8; ++j) {
        float m = j < d ? 1.f : 0.f;
        s0 += m * bf2f((unsigned short)rr[j]);
        s1 += m * bf2f((unsigned short)(rr[j] >> 16));
    }
    if (d > 8) {
        int n = min(d, CAP);
        const int* bq = bkt + 2 * (size_t)N_USER * CAP + (size_t)v * CAP;
        for (int j = 8; j < n; ++j) {
            unsigned int u = *(const unsigned int*)(h_u + (size_t)bq[j] * HID + lane * 2);
            s0 += bf2f((unsigned short)u);
            s1 += bf2f((unsigned short)(u >> 16));
        }
    }

    float rscale = ar_ui[0] * (float)d;
    float2 o;
    o.x = elu_f(rscale * bf2f((unsigned short)hv) + al_ui[0] * s0);
    o.y = elu_f(rscale * bf2f((unsigned short)(hv >> 16)) + al_ui[0] * s1);
    *(float2*)(out_i + (size_t)v * HID + lane * 2) = o;
}

// out_u = g_u @ W_out + b_out ; g_u: [M,128] bf16, Wto: [64,128] bf16 (transposed), out: [M,64] f32
__global__ __launch_bounds__(256) void out_user_kernel(
    const unsigned short* __restrict__ g_u, const unsigned short* __restrict__ Wto,
    const float* __restrict__ bo, float* __restrict__ out, int M)
{
    int wid  = threadIdx.x >> 6;
    int lane = threadIdx.x & 63;
    int row0 = (blockIdx.x * 4 + wid) * 16;
    if (row0 >= M) return;

    int r  = lane & 15;
    int kg = lane >> 4;

    bf16x8 a[4];
    const unsigned short* grow = g_u + (size_t)(row0 + r) * HID;
    #pragma unroll
    for (int kb = 0; kb < 4; ++kb)
        a[kb] = *(const bf16x8*)(grow + kb * 32 + kg * 8);

    #pragma unroll
    for (int nt = 0; nt < 4; ++nt) {
        f32x4 c = {0.f, 0.f, 0.f, 0.f};
        const unsigned short* wrow = Wto + (size_t)(nt * 16 + r) * HID;
        #pragma unroll
        for (int kb = 0; kb < 4; ++kb) {
            bf16x8 bf = *(const bf16x8*)(wrow + kb * 32 + kg * 8);
            c = __builtin_amdgcn_mfma_f32_16x16x32_bf16(a[kb], bf, c, 0, 0, 0);
        }
        float bias = bo[nt * 16 + r];
        #pragma unroll
        for (int i = 0; i < 4; ++i)
            out[(size_t)(row0 + kg * 4 + i) * OUT_DIM + nt * 16 + r] = c[i] + bias;
    }
}

extern "C" void kernel_launch(void* const* d_in, const int* in_sizes, int n_in,
                              void* d_out, int out_size, void* d_ws, size_t ws_size,
                              hipStream_t stream)
{
    const float* x_user = (const float*)d_in[0];
    const float* x_item = (const float*)d_in[1];
    const float* W_proj = (const float*)d_in[2];
    const float* b_proj = (const float*)d_in[3];
    const float* al_uu  = (const float*)d_in[4];
    const float* ar_uu  = (const float*)d_in[5];
    const float* al_iu  = (const float*)d_in[6];
    const float* ar_iu  = (const float*)d_in[7];
    const float* al_ui  = (const float*)d_in[8];
    const float* ar_ui  = (const float*)d_in[9];
    const float* W_out  = (const float*)d_in[10];
    const float* b_out  = (const float*)d_in[11];
    const int* edges_uu = (const int*)d_in[12];
    const int* edges_iu = (const int*)d_in[13];
    const int* edges_ui = (const int*)d_in[14];

    char* ws = (char*)d_ws;
    unsigned short* h_u = (unsigned short*)(ws);                   // 12,800,000
    unsigned short* h_i = (unsigned short*)(ws + 12800000);        // 12,800,000
    unsigned short* g_u = (unsigned short*)(ws + 25600000);        // 12,800,000
    unsigned short* Wtp = (unsigned short*)(ws + 38400000);        //     65,536
    unsigned short* Wto = (unsigned short*)(ws + 38465536);        //     16,384
    int* cnt            = (int*)(ws + 38481920);                   //    600,000 (3 x 50000)
    int* bkt            = (int*)(ws + 39081920);                   // 19,200,000 (3 x 50000 x 32)

    float* out_u = (float*)d_out;
    float* out_i = out_u + (size_t)N_USER * OUT_DIM;

    hipMemsetAsync(cnt, 0, 3 * N_USER * sizeof(int), stream);

    dim3 blk(256);
    transpose_w_kernel<<<dim3(160), blk, 0, stream>>>(W_proj, W_out, Wtp, Wto);

    proj_kernel<<<dim3(2 * PBLK), dim3(512), 0, stream>>>(x_user, x_item, Wtp, b_proj, h_u, h_i);

    fill_kernel<<<dim3(782, 3), blk, 0, stream>>>(edges_uu, edges_iu, edges_ui, cnt, bkt);

    gather_user_kernel<<<dim3(12500), blk, 0, stream>>>(h_u, h_i, cnt, bkt,
                                                        al_uu, ar_uu, al_iu, ar_iu, g_u);
    gather_item_kernel<<<dim3(12500), blk, 0, stream>>>(h_u, h_i, cnt, bkt,
                                                        al_ui, ar_ui, out_i);

    out_user_kernel<<<dim3(782), blk, 0, stream>>>(g_u, Wto, b_out, out_u, N_USER);
}